// Round 15
// baseline (140.154 us; speedup 1.0000x reference)
//
#include <hip/hip_runtime.h>
#include <math.h>

// CantorAttention: B=2, S=2048, DIM=512, H=8, HD=64, K=64
#define B_    2
#define S_    2048
#define DIM_  512
#define H_    8
#define HD_   64
#define K_    64
#define M_    (B_ * S_)          // 4096
#define NQKV_ (3 * DIM_)         // 1536

typedef __attribute__((ext_vector_type(8))) _Float16       half8;     // mfma A/B frag (8 f16)
typedef __attribute__((ext_vector_type(2))) _Float16       half2v;    // fdot2 operand
typedef __attribute__((ext_vector_type(8))) unsigned short ushort8v;  // 16B move
typedef __attribute__((ext_vector_type(4))) float          float4v;   // mfma C/D frag

// ---- fp16 helpers ----------------------------------------------------------
__device__ __forceinline__ unsigned short f2h(float f) {
    _Float16 h = (_Float16)f;
    unsigned short u; __builtin_memcpy(&u, &h, 2); return u;
}
__device__ __forceinline__ float h2f(unsigned short u) {
    _Float16 h; __builtin_memcpy(&h, &u, 2); return (float)h;
}

// async 16B global -> LDS (lane l lands at ldsbase + l*16)
__device__ __forceinline__ void load_lds16(const unsigned short* g, unsigned short* l) {
    __builtin_amdgcn_global_load_lds(
        (const __attribute__((address_space(1))) void*)g,
        (__attribute__((address_space(3))) void*)l, 16, 0, 0);
}

// ---------------------------------------------------------------------------
// prep_all: one kernel, block-range partitioned.
//   [0,1024): convert x fp32 -> xh fp16 (8 elems/thread; 1-term scheme)
//   [1024,1792): transpose Wqkv -> Wqh fp16 [N][Kd] (48 x 16 tiles of 32x32)
//   [1792,2048): transpose Wout -> Woh fp16 (16 x 16 tiles)
// ---------------------------------------------------------------------------
__global__ __launch_bounds__(256) void prep_all(
    const float* __restrict__ X, unsigned short* __restrict__ Xh,
    const float* __restrict__ Wq, unsigned short* __restrict__ Wqh,
    const float* __restrict__ Wo, unsigned short* __restrict__ Woh)
{
    __shared__ float tile[32][33];
    const int bid = blockIdx.x, t = threadIdx.x;

    if (bid < 1024) {
        size_t i = ((size_t)bid * 256 + t) * 8;
        float4 a = *(const float4*)&X[i];
        float4 b = *(const float4*)&X[i + 4];
        float f[8] = {a.x, a.y, a.z, a.w, b.x, b.y, b.z, b.w};
        ushort8v h;
        #pragma unroll
        for (int j = 0; j < 8; ++j) h[j] = f2h(f[j]);
        *(ushort8v*)&Xh[i] = h;
        return;
    }

    const float* W;
    unsigned short* Whi;
    int N, k0, n0;
    if (bid < 1792) {
        int idx = bid - 1024;                  // 768 blocks: 48 n-tiles x 16 k-tiles
        W = Wq; Whi = Wqh; N = NQKV_;
        n0 = (idx % 48) * 32; k0 = (idx / 48) * 32;
    } else {
        int idx = bid - 1792;                  // 256 blocks: 16 x 16
        W = Wo; Whi = Woh; N = DIM_;
        n0 = (idx % 16) * 32; k0 = (idx / 16) * 32;
    }
    const int c = t & 31, r8 = t >> 5;
    #pragma unroll
    for (int i = 0; i < 4; ++i) {
        int r = r8 + i * 8;
        tile[r][c] = W[(size_t)(k0 + r) * N + n0 + c];
    }
    __syncthreads();
    #pragma unroll
    for (int i = 0; i < 4; ++i) {
        int r = r8 + i * 8;                 // n offset
        Whi[(size_t)(n0 + r) * 512 + k0 + c] = f2h(tile[c][r]);   // Kd = 512
    }
}

// ---------------------------------------------------------------------------
// fp16 MFMA GEMM. TERMS=2: C=(Ah+Al)*Wh. TERMS=1: C=Ah*Wh (err ~2^-10).
// Double-buffered global_load_lds staging (prefetch a compute phase ahead).
//   mode 0: row-major fp32 C.
//   mode 1: qkv scatter -> Q/K/V all fp16, layout [B,H,S,HD].
// ---------------------------------------------------------------------------
template<int BM, int BN, int WM, int WN, int TERMS>
__global__ __launch_bounds__(256) void gemm_mfma(
    const unsigned short* __restrict__ Ahi, const unsigned short* __restrict__ Alo,
    const unsigned short* __restrict__ Wh,
    const float* __restrict__ bias, float* __restrict__ C,
    unsigned short* __restrict__ Qho, unsigned short* __restrict__ Kho,
    unsigned short* __restrict__ Vho,
    int N, int Kd, int mode)
{
    constexpr int TM = WM / 16, TN = WN / 16;
    constexpr int WAVES_N = BN / WN;
    __shared__ unsigned short Ah[2][BM][32];
    __shared__ unsigned short Al[TERMS == 2 ? 2 : 1][TERMS == 2 ? BM : 1][32];
    __shared__ unsigned short Bh[2][BN][32];

    const int t = threadIdx.x, lane = t & 63, wave = t >> 6;
    const int wm = (wave / WAVES_N) * WM, wn = (wave % WAVES_N) * WN;
    const int m0 = blockIdx.y * BM, n0 = blockIdx.x * BN;
    const int l15 = lane & 15, l4 = lane >> 4;

    const int srow = lane >> 2;          // 0..15
    const int scol = (lane & 3) * 8;     // 0,8,16,24

    float4v acc[TM][TN];
    #pragma unroll
    for (int i = 0; i < TM; ++i)
        #pragma unroll
        for (int j = 0; j < TN; ++j)
            #pragma unroll
            for (int r = 0; r < 4; ++r) acc[i][j][r] = 0.f;

    const int NK = Kd / 32;

    #pragma unroll
    for (int c = wave; c < BM / 16; c += 4) {
        size_t g = (size_t)(m0 + c * 16 + srow) * Kd + scol;
        load_lds16(&Ahi[g], &Ah[0][c * 16][0]);
        if constexpr (TERMS == 2) load_lds16(&Alo[g], &Al[0][c * 16][0]);
    }
    #pragma unroll
    for (int c = wave; c < BN / 16; c += 4) {
        size_t g = (size_t)(n0 + c * 16 + srow) * Kd + scol;
        load_lds16(&Wh[g], &Bh[0][c * 16][0]);
    }
    __syncthreads();

    for (int ks = 0; ks < NK; ++ks) {
        const int cur = ks & 1, nxt = cur ^ 1;

        if (ks + 1 < NK) {
            const int k1 = (ks + 1) * 32;
            #pragma unroll
            for (int c = wave; c < BM / 16; c += 4) {
                size_t g = (size_t)(m0 + c * 16 + srow) * Kd + k1 + scol;
                load_lds16(&Ahi[g], &Ah[nxt][c * 16][0]);
                if constexpr (TERMS == 2) load_lds16(&Alo[g], &Al[nxt][c * 16][0]);
            }
            #pragma unroll
            for (int c = wave; c < BN / 16; c += 4) {
                size_t g = (size_t)(n0 + c * 16 + srow) * Kd + k1 + scol;
                load_lds16(&Wh[g], &Bh[nxt][c * 16][0]);
            }
        }

        half8 fa_h[TM], fa_l[TM], fb[TN];
        #pragma unroll
        for (int im = 0; im < TM; ++im) {
            fa_h[im] = *(const half8*)&Ah[cur][wm + im * 16 + l15][l4 * 8];
            if constexpr (TERMS == 2)
                fa_l[im] = *(const half8*)&Al[cur][wm + im * 16 + l15][l4 * 8];
        }
        #pragma unroll
        for (int in = 0; in < TN; ++in)
            fb[in] = *(const half8*)&Bh[cur][wn + in * 16 + l15][l4 * 8];
        #pragma unroll
        for (int im = 0; im < TM; ++im)
            #pragma unroll
            for (int in = 0; in < TN; ++in) {
                acc[im][in] = __builtin_amdgcn_mfma_f32_16x16x32_f16(fa_h[im], fb[in], acc[im][in], 0, 0, 0);
                if constexpr (TERMS == 2)
                    acc[im][in] = __builtin_amdgcn_mfma_f32_16x16x32_f16(fa_l[im], fb[in], acc[im][in], 0, 0, 0);
            }

        __syncthreads();
    }

    // epilogue: D row = (lane>>4)*4 + reg, col = lane&15  [m89-verified layout]
    if (mode == 0) {
        #pragma unroll
        for (int in = 0; in < TN; ++in) {
            int n = n0 + wn + in * 16 + l15;
            float bv = bias[n];
            #pragma unroll
            for (int im = 0; im < TM; ++im) {
                int mb = m0 + wm + im * 16 + l4 * 4;
                #pragma unroll
                for (int r = 0; r < 4; ++r)
                    C[(size_t)(mb + r) * N + n] = acc[im][in][r] + bv;
            }
        }
    } else {
        #pragma unroll
        for (int in = 0; in < TN; ++in) {
            int n = n0 + wn + in * 16 + l15;
            int which = n >> 9, h = (n >> 6) & 7, d = n & 63;
            unsigned short* dst = (which == 0) ? Qho : (which == 1 ? Kho : Vho);
            float bv = bias[n];
            #pragma unroll
            for (int im = 0; im < TM; ++im) {
                int mb = m0 + wm + im * 16 + l4 * 4;
                #pragma unroll
                for (int r = 0; r < 4; ++r) {
                    int m = mb + r, b = m >> 11, s = m & 2047;
                    dst[(((size_t)b * H_ + h) * S_ + s) * HD_ + d] =
                        f2h(acc[im][in][r] + bv);
                }
            }
        }
    }
}

// ---------------------------------------------------------------------------
// Gathered attention — BARRIER-FREE / LDS-FREE. TWO queries per wave,
// XCD-pinned by (b,h). Q/K/V fp16.
// Phase 1: key j = pass*8 + (lane&7); q-slice chunk = lane>>3, loaded
// directly (16B/lane). After xor-reduce over lane>>3 (offs 8/16/32) every
// lane holds key pass*8+(lane&7); lane L keeps its own key's score via one
// cndmask per pass (pass == L>>3). No LDS, no __syncthreads; all waves
// fully independent. V prefetched before softmax. Output fp16. 4096 blocks.
// ---------------------------------------------------------------------------
__global__ __launch_bounds__(256) void attn_kernel(
    const unsigned short* __restrict__ Qh, const unsigned short* __restrict__ Kh,
    const unsigned short* __restrict__ Vh, const int* __restrict__ routes,
    unsigned short* __restrict__ Oh)
{
    const int wv = threadIdx.x >> 6, lane = threadIdx.x & 63;

    const int blk  = blockIdx.x;
    const int xcd  = blk & 7;
    const int idx  = blk >> 3;            // [0, 512)
    const int half = idx >> 8;            // 0 or 1
    const int sblk = idx & 255;           // [0, 256)
    const int bh   = xcd | (half << 3);   // [0, 16)
    const int s0   = sblk * 8 + wv * 2;   // this wave: s0, s0+1
    const int b    = bh >> 3, h = bh & 7;

    const int hi3 = lane >> 3;            // q-chunk / reduce group
    const int lo3 = lane & 7;             // key-in-pass

    // direct q loads: 16B = 8 f16 at chunk hi3 (lanes sharing hi3 broadcast)
    ushort8v qv0u = *(const ushort8v*)&Qh[((size_t)bh * S_ + s0) * HD_ + hi3 * 8];
    ushort8v qv1u = *(const ushort8v*)&Qh[((size_t)bh * S_ + s0 + 1) * HD_ + hi3 * 8];
    half2v qp0[4], qp1[4];
    __builtin_memcpy(qp0, &qv0u, 16);
    __builtin_memcpy(qp1, &qv1u, 16);

    const int r0 = routes[s0 * K_ + lane];
    const int r1 = routes[(s0 + 1) * K_ + lane];

    // phase 1: scores via fdot2. Key j = pass*8 + lo3; lane reads k-chunk hi3.
    const unsigned short* kbase = Kh + (size_t)bh * S_ * HD_;
    float sc0 = 0.f, sc1 = 0.f;
    #pragma unroll
    for (int pass = 0; pass < 8; ++pass) {
        int j = pass * 8 + lo3;
        int rj0 = __shfl(r0, j);
        int rj1 = __shfl(r1, j);
        ushort8v k0u = *(const ushort8v*)&kbase[(size_t)rj0 * HD_ + hi3 * 8];
        ushort8v k1u = *(const ushort8v*)&kbase[(size_t)rj1 * HD_ + hi3 * 8];
        half2v kp0[4], kp1[4];
        __builtin_memcpy(kp0, &k0u, 16);
        __builtin_memcpy(kp1, &k1u, 16);
        float pa = 0.f, pb = 0.f;
        #pragma unroll
        for (int i = 0; i < 4; ++i) {
            pa = __builtin_amdgcn_fdot2(qp0[i], kp0[i], pa, false);
            pb = __builtin_amdgcn_fdot2(qp1[i], kp1[i], pb, false);
        }
        // reduce across hi3 groups: all lanes get the full dot for key j
        pa += __shfl_xor(pa, 8);   pb += __shfl_xor(pb, 8);
        pa += __shfl_xor(pa, 16);  pb += __shfl_xor(pb, 16);
        pa += __shfl_xor(pa, 32);  pb += __shfl_xor(pb, 32);
        // lane keeps its own key (key == lane  <=>  pass == hi3)
        if (pass == hi3) { sc0 = pa; sc1 = pb; }
    }
    sc0 *= 0.125f;  sc1 *= 0.125f;

    // prefetch phase-2 V rows (addresses depend only on routes) — latency
    // overlaps the softmax shuffle chain below.
    const int kg = hi3, p8 = lo3;
    const unsigned short* vbase = Vh + (size_t)bh * S_ * HD_;
    ushort8v pv0[8], pv1[8];
    #pragma unroll
    for (int i = 0; i < 8; ++i) {
        int key = i * 8 + kg;
        int rj0 = __shfl(r0, key), rj1 = __shfl(r1, key);
        pv0[i] = *(const ushort8v*)&vbase[(size_t)rj0 * HD_ + p8 * 8];
        pv1[i] = *(const ushort8v*)&vbase[(size_t)rj1 * HD_ + p8 * 8];
    }

    // softmax (two independent shuffle chains); score for key=lane in lane
    float ma = sc0, mb = sc1;
    #pragma unroll
    for (int off = 32; off >= 1; off >>= 1) {
        ma = fmaxf(ma, __shfl_xor(ma, off));
        mb = fmaxf(mb, __shfl_xor(mb, off));
    }
    float ea = __expf(sc0 - ma), eb = __expf(sc1 - mb);
    float su_a = ea, su_b = eb;
    #pragma unroll
    for (int off = 32; off >= 1; off >>= 1) {
        su_a += __shfl_xor(su_a, off);
        su_b += __shfl_xor(su_b, off);
    }
    const float w0 = ea / su_a, w1 = eb / su_b;   // weight for key = lane

    // phase 2: FMA with prefetched V. lane = (key-group kg, d-slice p8).
    float ac0[8] = {0.f,0.f,0.f,0.f,0.f,0.f,0.f,0.f};
    float ac1[8] = {0.f,0.f,0.f,0.f,0.f,0.f,0.f,0.f};
    #pragma unroll
    for (int i = 0; i < 8; ++i) {
        int key = i * 8 + kg;
        float wj0 = __shfl(w0, key), wj1 = __shfl(w1, key);
        #pragma unroll
        for (int j = 0; j < 8; ++j) {
            ac0[j] += wj0 * h2f(pv0[i][j]);
            ac1[j] += wj1 * h2f(pv1[i][j]);
        }
    }
    // reduce across the 8 key-groups (lanes with same p8, kg varying)
    #pragma unroll
    for (int off = 8; off <= 32; off <<= 1) {
        #pragma unroll
        for (int j = 0; j < 8; ++j) {
            ac0[j] += __shfl_xor(ac0[j], off);
            ac1[j] += __shfl_xor(ac1[j], off);
        }
    }

    if (kg == 0) {
        ushort8v h0, h1;
        #pragma unroll
        for (int j = 0; j < 8; ++j) {
            h0[j] = f2h(ac0[j]);
            h1[j] = f2h(ac1[j]);
        }
        size_t oi0 = ((size_t)b * S_ + s0) * DIM_ + h * HD_ + p8 * 8;
        size_t oi1 = oi0 + DIM_;
        *(ushort8v*)&Oh[oi0] = h0;
        *(ushort8v*)&Oh[oi1] = h1;
    }
}

// ---------------------------------------------------------------------------
// ws layout (bytes):
//   0    Q fp16 4MB | 8M K fp16 4MB | 16M V fp16 4MB
//   24M  x_h / attn fp16 4MB
//   32M  Wqkv_h fp16 1.5M | +1.5M Wout_h fp16 0.5M
// ---------------------------------------------------------------------------
extern "C" void kernel_launch(void* const* d_in, const int* in_sizes, int n_in,
                              void* d_out, int out_size, void* d_ws, size_t ws_size,
                              hipStream_t stream)
{
    const float* x      = (const float*)d_in[0];
    const float* Wqkv   = (const float*)d_in[1];
    const float* bqkv   = (const float*)d_in[2];
    const float* Wout   = (const float*)d_in[3];
    const float* bout   = (const float*)d_in[4];
    const int*   routes = (const int*)d_in[5];
    float* out = (float*)d_out;

    char* w = (char*)d_ws;
    unsigned short* Qh = (unsigned short*)(w);
    unsigned short* Kh = (unsigned short*)(w + (8u << 20));
    unsigned short* Vh = (unsigned short*)(w + (16u << 20));
    unsigned short* xh = (unsigned short*)(w + (24u << 20));
    unsigned short* ah = xh;   // aliased: free after qkv gemm
    unsigned short* wqh = (unsigned short*)(w + (32u << 20));
    unsigned short* woh = (unsigned short*)(w + (32u << 20) + 1572864u);

    dim3 blk(256);

    // fused prep: x-convert (1024 blocks) + Wqkv transpose (768) + Wout (256)
    prep_all<<<dim3(2048), blk, 0, stream>>>(x, xh, Wqkv, wqh, Wout, woh);

    // qkv: M=4096, N=1536, K=512 -> 16x32 = 512 blocks, 1-term A
    gemm_mfma<128, 96, 64, 48, 1><<<dim3(NQKV_ / 96, M_ / 128), blk, 0, stream>>>(
        xh, nullptr, wqh, bqkv, nullptr, Qh, Kh, Vh, NQKV_, DIM_, 1);

    attn_kernel<<<dim3((B_ * H_ * S_) / 8), blk, 0, stream>>>(Qh, Kh, Vh, routes, ah);

    // out-proj: M=4096, N=512, K=512 -> 8x64 = 512 blocks, 1-term A
    gemm_mfma<64, 64, 32, 32, 1><<<dim3(DIM_ / 64, M_ / 64), blk, 0, stream>>>(
        ah, nullptr, woh, bout, out, nullptr, nullptr, nullptr, DIM_, DIM_, 0);
}

// Round 16
// 129.852 us; speedup vs baseline: 1.0793x; 1.0793x over previous
//
#include <hip/hip_runtime.h>
#include <math.h>

// CantorAttention: B=2, S=2048, DIM=512, H=8, HD=64, K=64
#define B_    2
#define S_    2048
#define DIM_  512
#define H_    8
#define HD_   64
#define K_    64
#define M_    (B_ * S_)          // 4096
#define NQKV_ (3 * DIM_)         // 1536

typedef __attribute__((ext_vector_type(8))) _Float16       half8;     // mfma A/B frag (8 f16)
typedef __attribute__((ext_vector_type(2))) _Float16       half2v;    // fdot2 operand
typedef __attribute__((ext_vector_type(8))) unsigned short ushort8v;  // 16B move
typedef __attribute__((ext_vector_type(4))) float          float4v;   // mfma C/D frag

// ---- fp16 helpers ----------------------------------------------------------
__device__ __forceinline__ unsigned short f2h(float f) {
    _Float16 h = (_Float16)f;
    unsigned short u; __builtin_memcpy(&u, &h, 2); return u;
}
__device__ __forceinline__ float h2f(unsigned short u) {
    _Float16 h; __builtin_memcpy(&h, &u, 2); return (float)h;
}

// async 16B global -> LDS (lane l lands at ldsbase + l*16)
__device__ __forceinline__ void load_lds16(const unsigned short* g, unsigned short* l) {
    __builtin_amdgcn_global_load_lds(
        (const __attribute__((address_space(1))) void*)g,
        (__attribute__((address_space(3))) void*)l, 16, 0, 0);
}

// ---------------------------------------------------------------------------
// prep_all: one kernel, block-range partitioned.
//   [0,1024): convert x fp32 -> xh fp16 (8 elems/thread; 1-term scheme)
//   [1024,1792): transpose Wqkv -> Wqh fp16 [N][Kd] (48 x 16 tiles of 32x32)
//   [1792,2048): transpose Wout -> Woh fp16 (16 x 16 tiles)
// ---------------------------------------------------------------------------
__global__ __launch_bounds__(256) void prep_all(
    const float* __restrict__ X, unsigned short* __restrict__ Xh,
    const float* __restrict__ Wq, unsigned short* __restrict__ Wqh,
    const float* __restrict__ Wo, unsigned short* __restrict__ Woh)
{
    __shared__ float tile[32][33];
    const int bid = blockIdx.x, t = threadIdx.x;

    if (bid < 1024) {
        size_t i = ((size_t)bid * 256 + t) * 8;
        float4 a = *(const float4*)&X[i];
        float4 b = *(const float4*)&X[i + 4];
        float f[8] = {a.x, a.y, a.z, a.w, b.x, b.y, b.z, b.w};
        ushort8v h;
        #pragma unroll
        for (int j = 0; j < 8; ++j) h[j] = f2h(f[j]);
        *(ushort8v*)&Xh[i] = h;
        return;
    }

    const float* W;
    unsigned short* Whi;
    int N, k0, n0;
    if (bid < 1792) {
        int idx = bid - 1024;                  // 768 blocks: 48 n-tiles x 16 k-tiles
        W = Wq; Whi = Wqh; N = NQKV_;
        n0 = (idx % 48) * 32; k0 = (idx / 48) * 32;
    } else {
        int idx = bid - 1792;                  // 256 blocks: 16 x 16
        W = Wo; Whi = Woh; N = DIM_;
        n0 = (idx % 16) * 32; k0 = (idx / 16) * 32;
    }
    const int c = t & 31, r8 = t >> 5;
    #pragma unroll
    for (int i = 0; i < 4; ++i) {
        int r = r8 + i * 8;
        tile[r][c] = W[(size_t)(k0 + r) * N + n0 + c];
    }
    __syncthreads();
    #pragma unroll
    for (int i = 0; i < 4; ++i) {
        int r = r8 + i * 8;                 // n offset
        Whi[(size_t)(n0 + r) * 512 + k0 + c] = f2h(tile[c][r]);   // Kd = 512
    }
}

// ---------------------------------------------------------------------------
// fp16 MFMA GEMM. TERMS=2: C=(Ah+Al)*Wh. TERMS=1: C=Ah*Wh (err ~2^-10).
// Double-buffered global_load_lds staging (prefetch a compute phase ahead).
//   mode 0: row-major fp32 C.
//   mode 1: qkv scatter -> Q/K/V all fp16, layout [B,H,S,HD].
// ---------------------------------------------------------------------------
template<int BM, int BN, int WM, int WN, int TERMS>
__global__ __launch_bounds__(256) void gemm_mfma(
    const unsigned short* __restrict__ Ahi, const unsigned short* __restrict__ Alo,
    const unsigned short* __restrict__ Wh,
    const float* __restrict__ bias, float* __restrict__ C,
    unsigned short* __restrict__ Qho, unsigned short* __restrict__ Kho,
    unsigned short* __restrict__ Vho,
    int N, int Kd, int mode)
{
    constexpr int TM = WM / 16, TN = WN / 16;
    constexpr int WAVES_N = BN / WN;
    __shared__ unsigned short Ah[2][BM][32];
    __shared__ unsigned short Al[TERMS == 2 ? 2 : 1][TERMS == 2 ? BM : 1][32];
    __shared__ unsigned short Bh[2][BN][32];

    const int t = threadIdx.x, lane = t & 63, wave = t >> 6;
    const int wm = (wave / WAVES_N) * WM, wn = (wave % WAVES_N) * WN;
    const int m0 = blockIdx.y * BM, n0 = blockIdx.x * BN;
    const int l15 = lane & 15, l4 = lane >> 4;

    const int srow = lane >> 2;          // 0..15
    const int scol = (lane & 3) * 8;     // 0,8,16,24

    float4v acc[TM][TN];
    #pragma unroll
    for (int i = 0; i < TM; ++i)
        #pragma unroll
        for (int j = 0; j < TN; ++j)
            #pragma unroll
            for (int r = 0; r < 4; ++r) acc[i][j][r] = 0.f;

    const int NK = Kd / 32;

    #pragma unroll
    for (int c = wave; c < BM / 16; c += 4) {
        size_t g = (size_t)(m0 + c * 16 + srow) * Kd + scol;
        load_lds16(&Ahi[g], &Ah[0][c * 16][0]);
        if constexpr (TERMS == 2) load_lds16(&Alo[g], &Al[0][c * 16][0]);
    }
    #pragma unroll
    for (int c = wave; c < BN / 16; c += 4) {
        size_t g = (size_t)(n0 + c * 16 + srow) * Kd + scol;
        load_lds16(&Wh[g], &Bh[0][c * 16][0]);
    }
    __syncthreads();

    for (int ks = 0; ks < NK; ++ks) {
        const int cur = ks & 1, nxt = cur ^ 1;

        if (ks + 1 < NK) {
            const int k1 = (ks + 1) * 32;
            #pragma unroll
            for (int c = wave; c < BM / 16; c += 4) {
                size_t g = (size_t)(m0 + c * 16 + srow) * Kd + k1 + scol;
                load_lds16(&Ahi[g], &Ah[nxt][c * 16][0]);
                if constexpr (TERMS == 2) load_lds16(&Alo[g], &Al[nxt][c * 16][0]);
            }
            #pragma unroll
            for (int c = wave; c < BN / 16; c += 4) {
                size_t g = (size_t)(n0 + c * 16 + srow) * Kd + k1 + scol;
                load_lds16(&Wh[g], &Bh[nxt][c * 16][0]);
            }
        }

        half8 fa_h[TM], fa_l[TM], fb[TN];
        #pragma unroll
        for (int im = 0; im < TM; ++im) {
            fa_h[im] = *(const half8*)&Ah[cur][wm + im * 16 + l15][l4 * 8];
            if constexpr (TERMS == 2)
                fa_l[im] = *(const half8*)&Al[cur][wm + im * 16 + l15][l4 * 8];
        }
        #pragma unroll
        for (int in = 0; in < TN; ++in)
            fb[in] = *(const half8*)&Bh[cur][wn + in * 16 + l15][l4 * 8];
        #pragma unroll
        for (int im = 0; im < TM; ++im)
            #pragma unroll
            for (int in = 0; in < TN; ++in) {
                acc[im][in] = __builtin_amdgcn_mfma_f32_16x16x32_f16(fa_h[im], fb[in], acc[im][in], 0, 0, 0);
                if constexpr (TERMS == 2)
                    acc[im][in] = __builtin_amdgcn_mfma_f32_16x16x32_f16(fa_l[im], fb[in], acc[im][in], 0, 0, 0);
            }

        __syncthreads();
    }

    // epilogue: D row = (lane>>4)*4 + reg, col = lane&15  [m89-verified layout]
    if (mode == 0) {
        #pragma unroll
        for (int in = 0; in < TN; ++in) {
            int n = n0 + wn + in * 16 + l15;
            float bv = bias[n];
            #pragma unroll
            for (int im = 0; im < TM; ++im) {
                int mb = m0 + wm + im * 16 + l4 * 4;
                #pragma unroll
                for (int r = 0; r < 4; ++r)
                    C[(size_t)(mb + r) * N + n] = acc[im][in][r] + bv;
            }
        }
    } else {
        #pragma unroll
        for (int in = 0; in < TN; ++in) {
            int n = n0 + wn + in * 16 + l15;
            int which = n >> 9, h = (n >> 6) & 7, d = n & 63;
            unsigned short* dst = (which == 0) ? Qho : (which == 1 ? Kho : Vho);
            float bv = bias[n];
            #pragma unroll
            for (int im = 0; im < TM; ++im) {
                int mb = m0 + wm + im * 16 + l4 * 4;
                #pragma unroll
                for (int r = 0; r < 4; ++r) {
                    int m = mb + r, b = m >> 11, s = m & 2047;
                    dst[(((size_t)b * H_ + h) * S_ + s) * HD_ + d] =
                        f2h(acc[im][in][r] + bv);
                }
            }
        }
    }
}

// ---------------------------------------------------------------------------
// Gathered attention — barrier-free / LDS-free WITH R13's coalesced loads.
// TWO queries per wave, XCD-pinned by (b,h). Q/K/V fp16.
// Phase 1: chunk p = lane&7, key-in-pass jl = lane>>3 (8 lanes = one 128B
// contiguous key-row segment — coalesced). Full xor-1/2/4 reduce gives every
// lane of a jl-group the key's score; keeping it at pass==p leaves lane L
// with the score of key swap(L) = (L&7)*8 + (L>>3). Softmax max/sum are
// permutation-invariant; phase 2 reads weight of key i*8+kg from lane
// kg*8+i (swap is an involution). Direct 16B q loads; V prefetched before
// softmax. Output fp16. 4096 blocks, zero LDS, zero barriers.
// ---------------------------------------------------------------------------
__global__ __launch_bounds__(256) void attn_kernel(
    const unsigned short* __restrict__ Qh, const unsigned short* __restrict__ Kh,
    const unsigned short* __restrict__ Vh, const int* __restrict__ routes,
    unsigned short* __restrict__ Oh)
{
    const int wv = threadIdx.x >> 6, lane = threadIdx.x & 63;

    const int blk  = blockIdx.x;
    const int xcd  = blk & 7;
    const int idx  = blk >> 3;            // [0, 512)
    const int half = idx >> 8;            // 0 or 1
    const int sblk = idx & 255;           // [0, 256)
    const int bh   = xcd | (half << 3);   // [0, 16)
    const int s0   = sblk * 8 + wv * 2;   // this wave: s0, s0+1
    const int b    = bh >> 3, h = bh & 7;

    const int p  = lane & 7;              // chunk (q/k) + pass selector
    const int jl = lane >> 3;             // key-in-pass

    // direct q loads: 16B chunk p (8 distinct addresses per wave, 2 lines)
    ushort8v qv0u = *(const ushort8v*)&Qh[((size_t)bh * S_ + s0) * HD_ + p * 8];
    ushort8v qv1u = *(const ushort8v*)&Qh[((size_t)bh * S_ + s0 + 1) * HD_ + p * 8];
    half2v qp0[4], qp1[4];
    __builtin_memcpy(qp0, &qv0u, 16);
    __builtin_memcpy(qp1, &qv1u, 16);

    const int r0 = routes[s0 * K_ + lane];
    const int r1 = routes[(s0 + 1) * K_ + lane];

    // phase 1: key j = pass*8 + jl, lane reads chunk p (coalesced 128B/key).
    const unsigned short* kbase = Kh + (size_t)bh * S_ * HD_;
    float sc0 = 0.f, sc1 = 0.f;           // score of key swap(lane)
    #pragma unroll
    for (int pass = 0; pass < 8; ++pass) {
        int j = pass * 8 + jl;
        int rj0 = __shfl(r0, j);
        int rj1 = __shfl(r1, j);
        ushort8v k0u = *(const ushort8v*)&kbase[(size_t)rj0 * HD_ + p * 8];
        ushort8v k1u = *(const ushort8v*)&kbase[(size_t)rj1 * HD_ + p * 8];
        half2v kp0[4], kp1[4];
        __builtin_memcpy(kp0, &k0u, 16);
        __builtin_memcpy(kp1, &k1u, 16);
        float pa = 0.f, pb = 0.f;
        #pragma unroll
        for (int i = 0; i < 4; ++i) {
            pa = __builtin_amdgcn_fdot2(qp0[i], kp0[i], pa, false);
            pb = __builtin_amdgcn_fdot2(qp1[i], kp1[i], pb, false);
        }
        // full reduce over the chunk dimension (xor 1,2,4): every lane of the
        // jl-group now holds key j's complete dot.
        pa += __shfl_xor(pa, 1);  pb += __shfl_xor(pb, 1);
        pa += __shfl_xor(pa, 2);  pb += __shfl_xor(pb, 2);
        pa += __shfl_xor(pa, 4);  pb += __shfl_xor(pb, 4);
        // lane (jl*8+p) keeps key p*8+jl = swap(lane) when pass == p
        if (pass == p) { sc0 = pa; sc1 = pb; }
    }
    sc0 *= 0.125f;  sc1 *= 0.125f;

    // prefetch phase-2 V rows (addresses depend only on routes) — latency
    // overlaps the softmax shuffle chains below. key = i*8+kg, chunk p8:
    // lanes kg*8.. share key, consecutive chunks — coalesced.
    const int kg = lane >> 3, p8 = lane & 7;
    const unsigned short* vbase = Vh + (size_t)bh * S_ * HD_;
    ushort8v pv0[8], pv1[8];
    #pragma unroll
    for (int i = 0; i < 8; ++i) {
        int key = i * 8 + kg;
        int rj0 = __shfl(r0, key), rj1 = __shfl(r1, key);
        pv0[i] = *(const ushort8v*)&vbase[(size_t)rj0 * HD_ + p8 * 8];
        pv1[i] = *(const ushort8v*)&vbase[(size_t)rj1 * HD_ + p8 * 8];
    }

    // softmax (permutation-invariant across lanes; lane holds key swap(lane))
    float ma = sc0, mb = sc1;
    #pragma unroll
    for (int off = 32; off >= 1; off >>= 1) {
        ma = fmaxf(ma, __shfl_xor(ma, off));
        mb = fmaxf(mb, __shfl_xor(mb, off));
    }
    float ea = __expf(sc0 - ma), eb = __expf(sc1 - mb);
    float su_a = ea, su_b = eb;
    #pragma unroll
    for (int off = 32; off >= 1; off >>= 1) {
        su_a += __shfl_xor(su_a, off);
        su_b += __shfl_xor(su_b, off);
    }
    const float w0 = ea / su_a, w1 = eb / su_b;   // weight of key swap(lane)

    // phase 2: weight of key i*8+kg lives in lane swap(i*8+kg) = kg*8+i.
    float ac0[8] = {0.f,0.f,0.f,0.f,0.f,0.f,0.f,0.f};
    float ac1[8] = {0.f,0.f,0.f,0.f,0.f,0.f,0.f,0.f};
    #pragma unroll
    for (int i = 0; i < 8; ++i) {
        float wj0 = __shfl(w0, kg * 8 + i), wj1 = __shfl(w1, kg * 8 + i);
        #pragma unroll
        for (int j = 0; j < 8; ++j) {
            ac0[j] += wj0 * h2f(pv0[i][j]);
            ac1[j] += wj1 * h2f(pv1[i][j]);
        }
    }
    // reduce across the 8 key-groups (lanes with same p8, kg varying)
    #pragma unroll
    for (int off = 8; off <= 32; off <<= 1) {
        #pragma unroll
        for (int j = 0; j < 8; ++j) {
            ac0[j] += __shfl_xor(ac0[j], off);
            ac1[j] += __shfl_xor(ac1[j], off);
        }
    }

    if (kg == 0) {
        ushort8v h0, h1;
        #pragma unroll
        for (int j = 0; j < 8; ++j) {
            h0[j] = f2h(ac0[j]);
            h1[j] = f2h(ac1[j]);
        }
        size_t oi0 = ((size_t)b * S_ + s0) * DIM_ + h * HD_ + p8 * 8;
        size_t oi1 = oi0 + DIM_;
        *(ushort8v*)&Oh[oi0] = h0;
        *(ushort8v*)&Oh[oi1] = h1;
    }
}

// ---------------------------------------------------------------------------
// ws layout (bytes):
//   0    Q fp16 4MB | 8M K fp16 4MB | 16M V fp16 4MB
//   24M  x_h / attn fp16 4MB
//   32M  Wqkv_h fp16 1.5M | +1.5M Wout_h fp16 0.5M
// ---------------------------------------------------------------------------
extern "C" void kernel_launch(void* const* d_in, const int* in_sizes, int n_in,
                              void* d_out, int out_size, void* d_ws, size_t ws_size,
                              hipStream_t stream)
{
    const float* x      = (const float*)d_in[0];
    const float* Wqkv   = (const float*)d_in[1];
    const float* bqkv   = (const float*)d_in[2];
    const float* Wout   = (const float*)d_in[3];
    const float* bout   = (const float*)d_in[4];
    const int*   routes = (const int*)d_in[5];
    float* out = (float*)d_out;

    char* w = (char*)d_ws;
    unsigned short* Qh = (unsigned short*)(w);
    unsigned short* Kh = (unsigned short*)(w + (8u << 20));
    unsigned short* Vh = (unsigned short*)(w + (16u << 20));
    unsigned short* xh = (unsigned short*)(w + (24u << 20));
    unsigned short* ah = xh;   // aliased: free after qkv gemm
    unsigned short* wqh = (unsigned short*)(w + (32u << 20));
    unsigned short* woh = (unsigned short*)(w + (32u << 20) + 1572864u);

    dim3 blk(256);

    // fused prep: x-convert (1024 blocks) + Wqkv transpose (768) + Wout (256)
    prep_all<<<dim3(2048), blk, 0, stream>>>(x, xh, Wqkv, wqh, Wout, woh);

    // qkv: M=4096, N=1536, K=512 -> 16x32 = 512 blocks, 1-term A
    gemm_mfma<128, 96, 64, 48, 1><<<dim3(NQKV_ / 96, M_ / 128), blk, 0, stream>>>(
        xh, nullptr, wqh, bqkv, nullptr, Qh, Kh, Vh, NQKV_, DIM_, 1);

    attn_kernel<<<dim3((B_ * H_ * S_) / 8), blk, 0, stream>>>(Qh, Kh, Vh, routes, ah);

    // out-proj: M=4096, N=512, K=512 -> 8x64 = 512 blocks, 1-term A
    gemm_mfma<64, 64, 32, 32, 1><<<dim3(DIM_ / 64, M_ / 64), blk, 0, stream>>>(
        ah, nullptr, woh, bout, out, nullptr, nullptr, nullptr, DIM_, DIM_, 0);
}

// Round 17
// 127.672 us; speedup vs baseline: 1.0978x; 1.0171x over previous
//
#include <hip/hip_runtime.h>
#include <math.h>

// CantorAttention: B=2, S=2048, DIM=512, H=8, HD=64, K=64
#define B_    2
#define S_    2048
#define DIM_  512
#define H_    8
#define HD_   64
#define K_    64
#define M_    (B_ * S_)          // 4096
#define NQKV_ (3 * DIM_)         // 1536

typedef __attribute__((ext_vector_type(8))) _Float16       half8;     // mfma A/B frag (8 f16)
typedef __attribute__((ext_vector_type(2))) _Float16       half2v;    // fdot2 operand
typedef __attribute__((ext_vector_type(8))) unsigned short ushort8v;  // 16B move
typedef __attribute__((ext_vector_type(4))) float          float4v;   // mfma C/D frag

// ---- fp16 helpers ----------------------------------------------------------
__device__ __forceinline__ unsigned short f2h(float f) {
    _Float16 h = (_Float16)f;
    unsigned short u; __builtin_memcpy(&u, &h, 2); return u;
}
__device__ __forceinline__ float h2f(unsigned short u) {
    _Float16 h; __builtin_memcpy(&h, &u, 2); return (float)h;
}

// async 16B global -> LDS (lane l lands at ldsbase + l*16)
__device__ __forceinline__ void load_lds16(const unsigned short* g, unsigned short* l) {
    __builtin_amdgcn_global_load_lds(
        (const __attribute__((address_space(1))) void*)g,
        (__attribute__((address_space(3))) void*)l, 16, 0, 0);
}

// ---------------------------------------------------------------------------
// prep_all: one kernel, block-range partitioned.
//   [0,1024): convert x fp32 -> xh fp16 (8 elems/thread; 1-term scheme)
//   [1024,1792): transpose Wqkv -> Wqh fp16 [N][Kd] (48 x 16 tiles of 32x32)
//   [1792,2048): transpose Wout -> Woh fp16 (16 x 16 tiles)
// ---------------------------------------------------------------------------
__global__ __launch_bounds__(256) void prep_all(
    const float* __restrict__ X, unsigned short* __restrict__ Xh,
    const float* __restrict__ Wq, unsigned short* __restrict__ Wqh,
    const float* __restrict__ Wo, unsigned short* __restrict__ Woh)
{
    __shared__ float tile[32][33];
    const int bid = blockIdx.x, t = threadIdx.x;

    if (bid < 1024) {
        size_t i = ((size_t)bid * 256 + t) * 8;
        float4 a = *(const float4*)&X[i];
        float4 b = *(const float4*)&X[i + 4];
        float f[8] = {a.x, a.y, a.z, a.w, b.x, b.y, b.z, b.w};
        ushort8v h;
        #pragma unroll
        for (int j = 0; j < 8; ++j) h[j] = f2h(f[j]);
        *(ushort8v*)&Xh[i] = h;
        return;
    }

    const float* W;
    unsigned short* Whi;
    int N, k0, n0;
    if (bid < 1792) {
        int idx = bid - 1024;                  // 768 blocks: 48 n-tiles x 16 k-tiles
        W = Wq; Whi = Wqh; N = NQKV_;
        n0 = (idx % 48) * 32; k0 = (idx / 48) * 32;
    } else {
        int idx = bid - 1792;                  // 256 blocks: 16 x 16
        W = Wo; Whi = Woh; N = DIM_;
        n0 = (idx % 16) * 32; k0 = (idx / 16) * 32;
    }
    const int c = t & 31, r8 = t >> 5;
    #pragma unroll
    for (int i = 0; i < 4; ++i) {
        int r = r8 + i * 8;
        tile[r][c] = W[(size_t)(k0 + r) * N + n0 + c];
    }
    __syncthreads();
    #pragma unroll
    for (int i = 0; i < 4; ++i) {
        int r = r8 + i * 8;                 // n offset
        Whi[(size_t)(n0 + r) * 512 + k0 + c] = f2h(tile[c][r]);   // Kd = 512
    }
}

// ---------------------------------------------------------------------------
// fp16 MFMA GEMM. TERMS=2: C=(Ah+Al)*Wh. TERMS=1: C=Ah*Wh (err ~2^-10).
// Double-buffered global_load_lds staging (prefetch a compute phase ahead).
//   mode 0: row-major fp32 C.
//   mode 1: qkv scatter -> Q/K/V all fp16, layout [B,H,S,HD].
// ---------------------------------------------------------------------------
template<int BM, int BN, int WM, int WN, int TERMS>
__global__ __launch_bounds__(256) void gemm_mfma(
    const unsigned short* __restrict__ Ahi, const unsigned short* __restrict__ Alo,
    const unsigned short* __restrict__ Wh,
    const float* __restrict__ bias, float* __restrict__ C,
    unsigned short* __restrict__ Qho, unsigned short* __restrict__ Kho,
    unsigned short* __restrict__ Vho,
    int N, int Kd, int mode)
{
    constexpr int TM = WM / 16, TN = WN / 16;
    constexpr int WAVES_N = BN / WN;
    __shared__ unsigned short Ah[2][BM][32];
    __shared__ unsigned short Al[TERMS == 2 ? 2 : 1][TERMS == 2 ? BM : 1][32];
    __shared__ unsigned short Bh[2][BN][32];

    const int t = threadIdx.x, lane = t & 63, wave = t >> 6;
    const int wm = (wave / WAVES_N) * WM, wn = (wave % WAVES_N) * WN;
    const int m0 = blockIdx.y * BM, n0 = blockIdx.x * BN;
    const int l15 = lane & 15, l4 = lane >> 4;

    const int srow = lane >> 2;          // 0..15
    const int scol = (lane & 3) * 8;     // 0,8,16,24

    float4v acc[TM][TN];
    #pragma unroll
    for (int i = 0; i < TM; ++i)
        #pragma unroll
        for (int j = 0; j < TN; ++j)
            #pragma unroll
            for (int r = 0; r < 4; ++r) acc[i][j][r] = 0.f;

    const int NK = Kd / 32;

    #pragma unroll
    for (int c = wave; c < BM / 16; c += 4) {
        size_t g = (size_t)(m0 + c * 16 + srow) * Kd + scol;
        load_lds16(&Ahi[g], &Ah[0][c * 16][0]);
        if constexpr (TERMS == 2) load_lds16(&Alo[g], &Al[0][c * 16][0]);
    }
    #pragma unroll
    for (int c = wave; c < BN / 16; c += 4) {
        size_t g = (size_t)(n0 + c * 16 + srow) * Kd + scol;
        load_lds16(&Wh[g], &Bh[0][c * 16][0]);
    }
    __syncthreads();

    for (int ks = 0; ks < NK; ++ks) {
        const int cur = ks & 1, nxt = cur ^ 1;

        if (ks + 1 < NK) {
            const int k1 = (ks + 1) * 32;
            #pragma unroll
            for (int c = wave; c < BM / 16; c += 4) {
                size_t g = (size_t)(m0 + c * 16 + srow) * Kd + k1 + scol;
                load_lds16(&Ahi[g], &Ah[nxt][c * 16][0]);
                if constexpr (TERMS == 2) load_lds16(&Alo[g], &Al[nxt][c * 16][0]);
            }
            #pragma unroll
            for (int c = wave; c < BN / 16; c += 4) {
                size_t g = (size_t)(n0 + c * 16 + srow) * Kd + k1 + scol;
                load_lds16(&Wh[g], &Bh[nxt][c * 16][0]);
            }
        }

        half8 fa_h[TM], fa_l[TM], fb[TN];
        #pragma unroll
        for (int im = 0; im < TM; ++im) {
            fa_h[im] = *(const half8*)&Ah[cur][wm + im * 16 + l15][l4 * 8];
            if constexpr (TERMS == 2)
                fa_l[im] = *(const half8*)&Al[cur][wm + im * 16 + l15][l4 * 8];
        }
        #pragma unroll
        for (int in = 0; in < TN; ++in)
            fb[in] = *(const half8*)&Bh[cur][wn + in * 16 + l15][l4 * 8];
        #pragma unroll
        for (int im = 0; im < TM; ++im)
            #pragma unroll
            for (int in = 0; in < TN; ++in) {
                acc[im][in] = __builtin_amdgcn_mfma_f32_16x16x32_f16(fa_h[im], fb[in], acc[im][in], 0, 0, 0);
                if constexpr (TERMS == 2)
                    acc[im][in] = __builtin_amdgcn_mfma_f32_16x16x32_f16(fa_l[im], fb[in], acc[im][in], 0, 0, 0);
            }

        __syncthreads();
    }

    // epilogue: D row = (lane>>4)*4 + reg, col = lane&15  [m89-verified layout]
    if (mode == 0) {
        #pragma unroll
        for (int in = 0; in < TN; ++in) {
            int n = n0 + wn + in * 16 + l15;
            float bv = bias[n];
            #pragma unroll
            for (int im = 0; im < TM; ++im) {
                int mb = m0 + wm + im * 16 + l4 * 4;
                #pragma unroll
                for (int r = 0; r < 4; ++r)
                    C[(size_t)(mb + r) * N + n] = acc[im][in][r] + bv;
            }
        }
    } else {
        #pragma unroll
        for (int in = 0; in < TN; ++in) {
            int n = n0 + wn + in * 16 + l15;
            int which = n >> 9, h = (n >> 6) & 7, d = n & 63;
            unsigned short* dst = (which == 0) ? Qho : (which == 1 ? Kho : Vho);
            float bv = bias[n];
            #pragma unroll
            for (int im = 0; im < TM; ++im) {
                int mb = m0 + wm + im * 16 + l4 * 4;
                #pragma unroll
                for (int r = 0; r < 4; ++r) {
                    int m = mb + r, b = m >> 11, s = m & 2047;
                    dst[(((size_t)b * H_ + h) * S_ + s) * HD_ + d] =
                        f2h(acc[im][in][r] + bv);
                }
            }
        }
    }
}

// ---------------------------------------------------------------------------
// Gathered attention — barrier-free / LDS-free, coalesced, DEEP-MLP version.
// __launch_bounds__(256,4) raises the VGPR budget to ~128 so the explicit
// load batches actually stay resident (at 48 VGPRs the compiler sank them
// to their uses, serializing ~32 L2 round-trips per wave).
// Phase 1: ALL 16 K-row loads issued before any fdot2. chunk p = lane&7,
// key-in-pass jl = lane>>3 (8 lanes = one contiguous 128B segment). Full
// xor-1/2/4 reduce + keep-at-pass==p leaves lane L with the score of key
// swap(L) = (L&7)*8+(L>>3); softmax is permutation-invariant; phase 2 reads
// the weight of key i*8+kg from lane kg*8+i. V rows prefetched before
// softmax. Output fp16. 4096 blocks, zero LDS, zero barriers.
// ---------------------------------------------------------------------------
__global__ __launch_bounds__(256, 4) void attn_kernel(
    const unsigned short* __restrict__ Qh, const unsigned short* __restrict__ Kh,
    const unsigned short* __restrict__ Vh, const int* __restrict__ routes,
    unsigned short* __restrict__ Oh)
{
    const int wv = threadIdx.x >> 6, lane = threadIdx.x & 63;

    const int blk  = blockIdx.x;
    const int xcd  = blk & 7;
    const int idx  = blk >> 3;            // [0, 512)
    const int half = idx >> 8;            // 0 or 1
    const int sblk = idx & 255;           // [0, 256)
    const int bh   = xcd | (half << 3);   // [0, 16)
    const int s0   = sblk * 8 + wv * 2;   // this wave: s0, s0+1
    const int b    = bh >> 3, h = bh & 7;

    const int p  = lane & 7;              // chunk (q/k) + pass selector
    const int jl = lane >> 3;             // key-in-pass

    // direct q loads: 16B chunk p (8 distinct addresses per wave, 2 lines)
    ushort8v qv0u = *(const ushort8v*)&Qh[((size_t)bh * S_ + s0) * HD_ + p * 8];
    ushort8v qv1u = *(const ushort8v*)&Qh[((size_t)bh * S_ + s0 + 1) * HD_ + p * 8];
    half2v qp0[4], qp1[4];
    __builtin_memcpy(qp0, &qv0u, 16);
    __builtin_memcpy(qp1, &qv1u, 16);

    const int r0 = routes[s0 * K_ + lane];
    const int r1 = routes[(s0 + 1) * K_ + lane];

    // ---- phase 1a: issue ALL 16 K loads (coalesced 128B per key-row) ----
    const unsigned short* kbase = Kh + (size_t)bh * S_ * HD_;
    ushort8v k0a[8], k1a[8];
    #pragma unroll
    for (int pass = 0; pass < 8; ++pass) {
        int j = pass * 8 + jl;
        int rj0 = __shfl(r0, j);
        int rj1 = __shfl(r1, j);
        k0a[pass] = *(const ushort8v*)&kbase[(size_t)rj0 * HD_ + p * 8];
        k1a[pass] = *(const ushort8v*)&kbase[(size_t)rj1 * HD_ + p * 8];
    }

    // ---- phase 1b: fdot2 + reduce; lane keeps key swap(lane) ----
    float sc0 = 0.f, sc1 = 0.f;
    #pragma unroll
    for (int pass = 0; pass < 8; ++pass) {
        half2v kp0[4], kp1[4];
        __builtin_memcpy(kp0, &k0a[pass], 16);
        __builtin_memcpy(kp1, &k1a[pass], 16);
        float pa = 0.f, pb = 0.f;
        #pragma unroll
        for (int i = 0; i < 4; ++i) {
            pa = __builtin_amdgcn_fdot2(qp0[i], kp0[i], pa, false);
            pb = __builtin_amdgcn_fdot2(qp1[i], kp1[i], pb, false);
        }
        pa += __shfl_xor(pa, 1);  pb += __shfl_xor(pb, 1);
        pa += __shfl_xor(pa, 2);  pb += __shfl_xor(pb, 2);
        pa += __shfl_xor(pa, 4);  pb += __shfl_xor(pb, 4);
        if (pass == p) { sc0 = pa; sc1 = pb; }
    }
    sc0 *= 0.125f;  sc1 *= 0.125f;

    // prefetch phase-2 V rows (registers freed by K batch) — latency
    // overlaps the softmax shuffle chains below.
    const int kg = lane >> 3, p8 = lane & 7;
    const unsigned short* vbase = Vh + (size_t)bh * S_ * HD_;
    ushort8v pv0[8], pv1[8];
    #pragma unroll
    for (int i = 0; i < 8; ++i) {
        int key = i * 8 + kg;
        int rj0 = __shfl(r0, key), rj1 = __shfl(r1, key);
        pv0[i] = *(const ushort8v*)&vbase[(size_t)rj0 * HD_ + p8 * 8];
        pv1[i] = *(const ushort8v*)&vbase[(size_t)rj1 * HD_ + p8 * 8];
    }

    // softmax (permutation-invariant across lanes; lane holds key swap(lane))
    float ma = sc0, mb = sc1;
    #pragma unroll
    for (int off = 32; off >= 1; off >>= 1) {
        ma = fmaxf(ma, __shfl_xor(ma, off));
        mb = fmaxf(mb, __shfl_xor(mb, off));
    }
    float ea = __expf(sc0 - ma), eb = __expf(sc1 - mb);
    float su_a = ea, su_b = eb;
    #pragma unroll
    for (int off = 32; off >= 1; off >>= 1) {
        su_a += __shfl_xor(su_a, off);
        su_b += __shfl_xor(su_b, off);
    }
    const float w0 = ea / su_a, w1 = eb / su_b;   // weight of key swap(lane)

    // phase 2: weight of key i*8+kg lives in lane swap(i*8+kg) = kg*8+i.
    float ac0[8] = {0.f,0.f,0.f,0.f,0.f,0.f,0.f,0.f};
    float ac1[8] = {0.f,0.f,0.f,0.f,0.f,0.f,0.f,0.f};
    #pragma unroll
    for (int i = 0; i < 8; ++i) {
        float wj0 = __shfl(w0, kg * 8 + i), wj1 = __shfl(w1, kg * 8 + i);
        #pragma unroll
        for (int j = 0; j < 8; ++j) {
            ac0[j] += wj0 * h2f(pv0[i][j]);
            ac1[j] += wj1 * h2f(pv1[i][j]);
        }
    }
    // reduce across the 8 key-groups (lanes with same p8, kg varying)
    #pragma unroll
    for (int off = 8; off <= 32; off <<= 1) {
        #pragma unroll
        for (int j = 0; j < 8; ++j) {
            ac0[j] += __shfl_xor(ac0[j], off);
            ac1[j] += __shfl_xor(ac1[j], off);
        }
    }

    if (kg == 0) {
        ushort8v h0, h1;
        #pragma unroll
        for (int j = 0; j < 8; ++j) {
            h0[j] = f2h(ac0[j]);
            h1[j] = f2h(ac1[j]);
        }
        size_t oi0 = ((size_t)b * S_ + s0) * DIM_ + h * HD_ + p8 * 8;
        size_t oi1 = oi0 + DIM_;
        *(ushort8v*)&Oh[oi0] = h0;
        *(ushort8v*)&Oh[oi1] = h1;
    }
}

// ---------------------------------------------------------------------------
// ws layout (bytes):
//   0    Q fp16 4MB | 8M K fp16 4MB | 16M V fp16 4MB
//   24M  x_h / attn fp16 4MB
//   32M  Wqkv_h fp16 1.5M | +1.5M Wout_h fp16 0.5M
// ---------------------------------------------------------------------------
extern "C" void kernel_launch(void* const* d_in, const int* in_sizes, int n_in,
                              void* d_out, int out_size, void* d_ws, size_t ws_size,
                              hipStream_t stream)
{
    const float* x      = (const float*)d_in[0];
    const float* Wqkv   = (const float*)d_in[1];
    const float* bqkv   = (const float*)d_in[2];
    const float* Wout   = (const float*)d_in[3];
    const float* bout   = (const float*)d_in[4];
    const int*   routes = (const int*)d_in[5];
    float* out = (float*)d_out;

    char* w = (char*)d_ws;
    unsigned short* Qh = (unsigned short*)(w);
    unsigned short* Kh = (unsigned short*)(w + (8u << 20));
    unsigned short* Vh = (unsigned short*)(w + (16u << 20));
    unsigned short* xh = (unsigned short*)(w + (24u << 20));
    unsigned short* ah = xh;   // aliased: free after qkv gemm
    unsigned short* wqh = (unsigned short*)(w + (32u << 20));
    unsigned short* woh = (unsigned short*)(w + (32u << 20) + 1572864u);

    dim3 blk(256);

    // fused prep: x-convert (1024 blocks) + Wqkv transpose (768) + Wout (256)
    prep_all<<<dim3(2048), blk, 0, stream>>>(x, xh, Wqkv, wqh, Wout, woh);

    // qkv: M=4096, N=1536, K=512 -> 16x32 = 512 blocks, 1-term A
    gemm_mfma<128, 96, 64, 48, 1><<<dim3(NQKV_ / 96, M_ / 128), blk, 0, stream>>>(
        xh, nullptr, wqh, bqkv, nullptr, Qh, Kh, Vh, NQKV_, DIM_, 1);

    attn_kernel<<<dim3((B_ * H_ * S_) / 8), blk, 0, stream>>>(Qh, Kh, Vh, routes, ah);

    // out-proj: M=4096, N=512, K=512 -> 8x64 = 512 blocks, 1-term A
    gemm_mfma<64, 64, 32, 32, 1><<<dim3(DIM_ / 64, M_ / 64), blk, 0, stream>>>(
        ah, nullptr, woh, bout, out, nullptr, nullptr, nullptr, DIM_, DIM_, 0);
}